// Round 1
// baseline (4564.614 us; speedup 1.0000x reference)
//
#include <hip/hip_runtime.h>

#define BATCH 8
#define NNODE 10000
#define NEDGE 320000
#define HD    128
#define NROW  (BATCH * NNODE)   // 80000 rows total

__device__ __forceinline__ void fma4(float4& a, float s, const float4& w) {
    a.x += s * w.x; a.y += s * w.y; a.z += s * w.z; a.w += s * w.w;
}

// deg[b*N + src[b,e]] += adj_val[b,e]
__global__ __launch_bounds__(256) void k_deg(const float* __restrict__ adj,
                                             const int* __restrict__ src,
                                             float* __restrict__ deg) {
    int idx = blockIdx.x * 256 + threadIdx.x;       // exactly B*E threads
    int b = idx / NEDGE;
    atomicAdd(&deg[b * NNODE + src[idx]], adj[idx]);
}

// Y[row,:] = (x[row,:] @ theta) * rsqrt(deg[row]+1e-6)
__global__ __launch_bounds__(512) void k_theta(const float* __restrict__ x,
                                               const float* __restrict__ theta,
                                               const float* __restrict__ deg,
                                               float* __restrict__ Y) {
    __shared__ float sw[HD * HD];                   // 64 KiB
    int tx = threadIdx.x;
    for (int i = tx; i < HD * HD / 4; i += 512)
        ((float4*)sw)[i] = ((const float4*)theta)[i];
    __syncthreads();

    int c  = tx & 31;                               // col group: cols 4c..4c+3
    int rs = tx >> 5;                               // 0..15
    long row0 = (long)blockIdx.x * 64 + rs * 4;     // 4 rows per thread
    const float* xp = x + row0 * HD;

    float4 acc[4] = {};
    for (int h = 0; h < HD; h += 4) {
        float4 w0 = ((const float4*)(sw + (h + 0) * HD))[c];
        float4 w1 = ((const float4*)(sw + (h + 1) * HD))[c];
        float4 w2 = ((const float4*)(sw + (h + 2) * HD))[c];
        float4 w3 = ((const float4*)(sw + (h + 3) * HD))[c];
        #pragma unroll
        for (int j = 0; j < 4; ++j) {
            float4 xv = *(const float4*)(xp + j * HD + h);
            fma4(acc[j], xv.x, w0);
            fma4(acc[j], xv.y, w1);
            fma4(acc[j], xv.z, w2);
            fma4(acc[j], xv.w, w3);
        }
    }
    #pragma unroll
    for (int j = 0; j < 4; ++j) {
        float nrm = rsqrtf(deg[row0 + j] + 1e-6f);
        float4 r;
        r.x = acc[j].x * nrm; r.y = acc[j].y * nrm;
        r.z = acc[j].z * nrm; r.w = acc[j].w * nrm;
        ((float4*)(Y + (row0 + j) * HD))[c] = r;
    }
}

// out[b, src, :] += adj_val * Y[b, dst, :]   (32 threads per edge, 4 cols each)
__global__ __launch_bounds__(256) void k_spmm(const float* __restrict__ adj,
                                              const int* __restrict__ src,
                                              const int* __restrict__ dst,
                                              const float* __restrict__ Y,
                                              float* __restrict__ out) {
    int tx = threadIdx.x;
    long eg = (long)blockIdx.x * 8 + (tx >> 5);     // edge index over B*E
    int c = tx & 31;
    int b = (int)(eg / NEDGE);
    int s = src[eg], d = dst[eg];
    float v = adj[eg];
    const float4 y = ((const float4*)(Y + ((long)b * NNODE + d) * HD))[c];
    float* op = out + ((long)b * NNODE + s) * HD + 4 * c;
    atomicAdd(op + 0, v * y.x);
    atomicAdd(op + 1, v * y.y);
    atomicAdd(op + 2, v * y.z);
    atomicAdd(op + 3, v * y.w);
}

// out[row,:] = gate * (Z[row,:]*norm) + (1-gate) * (x@W_h);  gate = sigmoid(x@W_t + b_t)
__global__ __launch_bounds__(512) void k_final(const float* __restrict__ x,
                                               const float* __restrict__ Wt,
                                               const float* __restrict__ bt,
                                               const float* __restrict__ Wh,
                                               const float* __restrict__ deg,
                                               float* __restrict__ out) {
    __shared__ float sw[HD * HD];                   // 64 KiB, reused for Wt then Wh
    int tx = threadIdx.x;
    int c  = tx & 31;
    int rs = tx >> 5;
    long row0 = (long)blockIdx.x * 64 + rs * 4;
    const float* xp = x + row0 * HD;

    float4 at[4] = {};
    float4 ah[4] = {};

    // ---- phase 0: W_t -> at ----
    for (int i = tx; i < HD * HD / 4; i += 512)
        ((float4*)sw)[i] = ((const float4*)Wt)[i];
    __syncthreads();
    for (int h = 0; h < HD; h += 4) {
        float4 w0 = ((const float4*)(sw + (h + 0) * HD))[c];
        float4 w1 = ((const float4*)(sw + (h + 1) * HD))[c];
        float4 w2 = ((const float4*)(sw + (h + 2) * HD))[c];
        float4 w3 = ((const float4*)(sw + (h + 3) * HD))[c];
        #pragma unroll
        for (int j = 0; j < 4; ++j) {
            float4 xv = *(const float4*)(xp + j * HD + h);
            fma4(at[j], xv.x, w0);
            fma4(at[j], xv.y, w1);
            fma4(at[j], xv.z, w2);
            fma4(at[j], xv.w, w3);
        }
    }
    __syncthreads();   // all reads of sw done

    // ---- phase 1: W_h -> ah ----
    for (int i = tx; i < HD * HD / 4; i += 512)
        ((float4*)sw)[i] = ((const float4*)Wh)[i];
    __syncthreads();
    for (int h = 0; h < HD; h += 4) {
        float4 w0 = ((const float4*)(sw + (h + 0) * HD))[c];
        float4 w1 = ((const float4*)(sw + (h + 1) * HD))[c];
        float4 w2 = ((const float4*)(sw + (h + 2) * HD))[c];
        float4 w3 = ((const float4*)(sw + (h + 3) * HD))[c];
        #pragma unroll
        for (int j = 0; j < 4; ++j) {
            float4 xv = *(const float4*)(xp + j * HD + h);
            fma4(ah[j], xv.x, w0);
            fma4(ah[j], xv.y, w1);
            fma4(ah[j], xv.z, w2);
            fma4(ah[j], xv.w, w3);
        }
    }

    float4 b4 = ((const float4*)bt)[c];
    #pragma unroll
    for (int j = 0; j < 4; ++j) {
        long row = row0 + j;
        float nrm = rsqrtf(deg[row] + 1e-6f);
        float4* orow = (float4*)(out + row * HD) + c;
        float4 z = *orow;
        float4 g, r;
        g.x = 1.f / (1.f + __expf(-(at[j].x + b4.x)));
        g.y = 1.f / (1.f + __expf(-(at[j].y + b4.y)));
        g.z = 1.f / (1.f + __expf(-(at[j].z + b4.z)));
        g.w = 1.f / (1.f + __expf(-(at[j].w + b4.w)));
        r.x = g.x * (z.x * nrm) + (1.f - g.x) * ah[j].x;
        r.y = g.y * (z.y * nrm) + (1.f - g.y) * ah[j].y;
        r.z = g.z * (z.z * nrm) + (1.f - g.z) * ah[j].z;
        r.w = g.w * (z.w * nrm) + (1.f - g.w) * ah[j].w;
        *orow = r;
    }
}

extern "C" void kernel_launch(void* const* d_in, const int* in_sizes, int n_in,
                              void* d_out, int out_size, void* d_ws, size_t ws_size,
                              hipStream_t stream) {
    const float* x     = (const float*)d_in[0];
    const float* adj   = (const float*)d_in[1];
    const int*   src   = (const int*)d_in[2];
    const int*   dst   = (const int*)d_in[3];
    const float* Wt    = (const float*)d_in[4];
    const float* bt    = (const float*)d_in[5];
    const float* Wh    = (const float*)d_in[6];
    const float* theta = (const float*)d_in[7];
    float* out = (float*)d_out;

    float* deg = (float*)d_ws;                 // NROW floats (320000 B, 16B-aligned)
    float* Y   = deg + NROW;                   // NROW*HD floats (~41 MB)

    hipMemsetAsync(deg, 0, (size_t)NROW * sizeof(float), stream);
    hipMemsetAsync(out, 0, (size_t)NROW * HD * sizeof(float), stream);

    k_deg  <<<BATCH * NEDGE / 256, 256, 0, stream>>>(adj, src, deg);
    k_theta<<<NROW / 64,           512, 0, stream>>>(x, theta, deg, Y);
    k_spmm <<<BATCH * NEDGE / 8,   256, 0, stream>>>(adj, src, dst, Y, out);
    k_final<<<NROW / 64,           512, 0, stream>>>(x, Wt, bt, Wh, deg, out);
}

// Round 2
// 963.228 us; speedup vs baseline: 4.7389x; 4.7389x over previous
//
#include <hip/hip_runtime.h>

#define BATCH 8
#define NNODE 10000
#define NEDGE 320000
#define HD    128
#define NROW  (BATCH * NNODE)   // 80000 rows
#define NEDG_TOT (BATCH * NEDGE) // 2.56M edges

__device__ __forceinline__ void fma4(float4& a, float s, const float4& w) {
    a.x += s * w.x; a.y += s * w.y; a.z += s * w.z; a.w += s * w.w;
}

// per-row: float degree sum + int edge count
__global__ __launch_bounds__(256) void k_deg(const float* __restrict__ adj,
                                             const int* __restrict__ src,
                                             float* __restrict__ deg,
                                             int* __restrict__ cnt) {
    int idx = blockIdx.x * 256 + threadIdx.x;       // exactly B*E threads
    int b = idx / NEDGE;
    int r = b * NNODE + src[idx];
    atomicAdd(&deg[r], adj[idx]);
    atomicAdd(&cnt[r], 1);
}

// exclusive scan of cnt[NROW] -> rowptr, cursor (single block, 1024 threads)
__global__ __launch_bounds__(1024) void k_scan(const int* __restrict__ cnt,
                                               int* __restrict__ rowptr,
                                               int* __restrict__ cursor) {
    __shared__ int part[1024];
    const int CHUNK = (NROW + 1023) / 1024;         // 79
    int t = threadIdx.x;
    int begin = t * CHUNK;
    int end = begin + CHUNK; if (end > NROW) end = NROW;
    int s = 0;
    for (int i = begin; i < end; ++i) s += cnt[i];
    part[t] = s;
    __syncthreads();
    for (int off = 1; off < 1024; off <<= 1) {      // Hillis-Steele inclusive
        int v = part[t];
        int add = (t >= off) ? part[t - off] : 0;
        __syncthreads();
        part[t] = v + add;
        __syncthreads();
    }
    int run = (t == 0) ? 0 : part[t - 1];           // exclusive base
    for (int i = begin; i < end; ++i) {
        rowptr[i] = run; cursor[i] = run;
        run += cnt[i];
    }
}

// bucket edges: perm[pos] = global edge idx, grouped by (b, src)
__global__ __launch_bounds__(256) void k_scatter(const int* __restrict__ src,
                                                 int* __restrict__ cursor,
                                                 int* __restrict__ perm) {
    int idx = blockIdx.x * 256 + threadIdx.x;
    int b = idx / NEDGE;
    int r = b * NNODE + src[idx];
    int pos = atomicAdd(&cursor[r], 1);
    perm[pos] = idx;
}

// Y[row,:] = (x[row,:] @ theta) * rsqrt(deg[row]+1e-6)
__global__ __launch_bounds__(512) void k_theta(const float* __restrict__ x,
                                               const float* __restrict__ theta,
                                               const float* __restrict__ deg,
                                               float* __restrict__ Y) {
    __shared__ float sw[HD * HD];                   // 64 KiB
    int tx = threadIdx.x;
    for (int i = tx; i < HD * HD / 4; i += 512)
        ((float4*)sw)[i] = ((const float4*)theta)[i];
    __syncthreads();

    int c  = tx & 31;
    int rs = tx >> 5;
    long row0 = (long)blockIdx.x * 64 + rs * 4;
    const float* xp = x + row0 * HD;

    float4 acc[4] = {};
    for (int h = 0; h < HD; h += 4) {
        float4 w0 = ((const float4*)(sw + (h + 0) * HD))[c];
        float4 w1 = ((const float4*)(sw + (h + 1) * HD))[c];
        float4 w2 = ((const float4*)(sw + (h + 2) * HD))[c];
        float4 w3 = ((const float4*)(sw + (h + 3) * HD))[c];
        #pragma unroll
        for (int j = 0; j < 4; ++j) {
            float4 xv = *(const float4*)(xp + j * HD + h);
            fma4(acc[j], xv.x, w0);
            fma4(acc[j], xv.y, w1);
            fma4(acc[j], xv.z, w2);
            fma4(acc[j], xv.w, w3);
        }
    }
    #pragma unroll
    for (int j = 0; j < 4; ++j) {
        float nrm = rsqrtf(deg[row0 + j] + 1e-6f);
        float4 r;
        r.x = acc[j].x * nrm; r.y = acc[j].y * nrm;
        r.z = acc[j].z * nrm; r.w = acc[j].w * nrm;
        ((float4*)(Y + (row0 + j) * HD))[c] = r;
    }
}

// gather SpMM: out[r,:] = norm[r] * sum_{e in bucket(r)} adj[e] * Y[b, dst[e], :]
// one wave per row, float2 per lane (64*2 = 128 cols), no atomics
__global__ __launch_bounds__(256) void k_gather(const int* __restrict__ rowptr,
                                                const int* __restrict__ cnt,
                                                const int* __restrict__ perm,
                                                const int* __restrict__ dst,
                                                const float* __restrict__ adj,
                                                const float* __restrict__ Y,
                                                const float* __restrict__ deg,
                                                float* __restrict__ out) {
    int wave = threadIdx.x >> 6, lane = threadIdx.x & 63;
    long r = (long)blockIdx.x * 4 + wave;
    int b = (int)(r / NNODE);
    const float* Yb = Y + (long)b * NNODE * HD + 2 * lane;
    int p0 = rowptr[r], n = cnt[r];
    float ax = 0.f, ay = 0.f;
    if (n > 0) {
        int e = perm[p0];
        int d = dst[e];
        float v = adj[e];
        for (int i = 1; i < n; ++i) {
            int e2 = perm[p0 + i];          // prefetch next edge meta
            int d2 = dst[e2];
            float v2 = adj[e2];
            const float2 y = *(const float2*)(Yb + (long)d * HD);
            ax += v * y.x; ay += v * y.y;
            d = d2; v = v2;
        }
        const float2 y = *(const float2*)(Yb + (long)d * HD);
        ax += v * y.x; ay += v * y.y;
    }
    float nrm = rsqrtf(deg[r] + 1e-6f);
    ((float2*)(out + r * HD))[lane] = make_float2(ax * nrm, ay * nrm);
}

// out[row,:] = gate * z + (1-gate) * (x@W_h);  gate = sigmoid(x@W_t + b_t); z pre-normed
__global__ __launch_bounds__(512) void k_final(const float* __restrict__ x,
                                               const float* __restrict__ Wt,
                                               const float* __restrict__ bt,
                                               const float* __restrict__ Wh,
                                               float* __restrict__ out) {
    __shared__ float sw[HD * HD];                   // 64 KiB, Wt then Wh
    int tx = threadIdx.x;
    int c  = tx & 31;
    int rs = tx >> 5;
    long row0 = (long)blockIdx.x * 64 + rs * 4;
    const float* xp = x + row0 * HD;

    float4 at[4] = {};
    float4 ah[4] = {};

    for (int i = tx; i < HD * HD / 4; i += 512)
        ((float4*)sw)[i] = ((const float4*)Wt)[i];
    __syncthreads();
    for (int h = 0; h < HD; h += 4) {
        float4 w0 = ((const float4*)(sw + (h + 0) * HD))[c];
        float4 w1 = ((const float4*)(sw + (h + 1) * HD))[c];
        float4 w2 = ((const float4*)(sw + (h + 2) * HD))[c];
        float4 w3 = ((const float4*)(sw + (h + 3) * HD))[c];
        #pragma unroll
        for (int j = 0; j < 4; ++j) {
            float4 xv = *(const float4*)(xp + j * HD + h);
            fma4(at[j], xv.x, w0);
            fma4(at[j], xv.y, w1);
            fma4(at[j], xv.z, w2);
            fma4(at[j], xv.w, w3);
        }
    }
    __syncthreads();

    for (int i = tx; i < HD * HD / 4; i += 512)
        ((float4*)sw)[i] = ((const float4*)Wh)[i];
    __syncthreads();
    for (int h = 0; h < HD; h += 4) {
        float4 w0 = ((const float4*)(sw + (h + 0) * HD))[c];
        float4 w1 = ((const float4*)(sw + (h + 1) * HD))[c];
        float4 w2 = ((const float4*)(sw + (h + 2) * HD))[c];
        float4 w3 = ((const float4*)(sw + (h + 3) * HD))[c];
        #pragma unroll
        for (int j = 0; j < 4; ++j) {
            float4 xv = *(const float4*)(xp + j * HD + h);
            fma4(ah[j], xv.x, w0);
            fma4(ah[j], xv.y, w1);
            fma4(ah[j], xv.z, w2);
            fma4(ah[j], xv.w, w3);
        }
    }

    float4 b4 = ((const float4*)bt)[c];
    #pragma unroll
    for (int j = 0; j < 4; ++j) {
        long row = row0 + j;
        float4* orow = (float4*)(out + row * HD) + c;
        float4 z = *orow;
        float4 g, r;
        g.x = 1.f / (1.f + __expf(-(at[j].x + b4.x)));
        g.y = 1.f / (1.f + __expf(-(at[j].y + b4.y)));
        g.z = 1.f / (1.f + __expf(-(at[j].z + b4.z)));
        g.w = 1.f / (1.f + __expf(-(at[j].w + b4.w)));
        r.x = g.x * z.x + (1.f - g.x) * ah[j].x;
        r.y = g.y * z.y + (1.f - g.y) * ah[j].y;
        r.z = g.z * z.z + (1.f - g.z) * ah[j].z;
        r.w = g.w * z.w + (1.f - g.w) * ah[j].w;
        *orow = r;
    }
}

extern "C" void kernel_launch(void* const* d_in, const int* in_sizes, int n_in,
                              void* d_out, int out_size, void* d_ws, size_t ws_size,
                              hipStream_t stream) {
    const float* x     = (const float*)d_in[0];
    const float* adj   = (const float*)d_in[1];
    const int*   src   = (const int*)d_in[2];
    const int*   dst   = (const int*)d_in[3];
    const float* Wt    = (const float*)d_in[4];
    const float* bt    = (const float*)d_in[5];
    const float* Wh    = (const float*)d_in[6];
    const float* theta = (const float*)d_in[7];
    float* out = (float*)d_out;

    // workspace layout (~52.5 MB)
    float* deg    = (float*)d_ws;            // NROW
    int*   cnt    = (int*)(deg + NROW);      // NROW
    int*   rowptr = cnt + NROW;              // NROW
    int*   cursor = rowptr + NROW;           // NROW
    int*   perm   = cursor + NROW;           // NEDG_TOT
    float* Y      = (float*)(perm + NEDG_TOT); // NROW*HD

    hipMemsetAsync(deg, 0, (size_t)NROW * 2 * sizeof(float), stream); // deg + cnt

    k_deg    <<<NEDG_TOT / 256, 256, 0, stream>>>(adj, src, deg, cnt);
    k_scan   <<<1, 1024, 0, stream>>>(cnt, rowptr, cursor);
    k_scatter<<<NEDG_TOT / 256, 256, 0, stream>>>(src, cursor, perm);
    k_theta  <<<NROW / 64, 512, 0, stream>>>(x, theta, deg, Y);
    k_gather <<<NROW / 4, 256, 0, stream>>>(rowptr, cnt, perm, dst, adj, Y, deg, out);
    k_final  <<<NROW / 64, 512, 0, stream>>>(x, Wt, bt, Wh, out);
}

// Round 3
// 570.075 us; speedup vs baseline: 8.0070x; 1.6896x over previous
//
#include <hip/hip_runtime.h>

#define BATCH 8
#define NNODE 10000
#define NEDGE 320000
#define HD    128
#define NROW  (BATCH * NNODE)     // 80000 rows
#define NEDG_TOT (BATCH * NEDGE)  // 2.56M edges
#define SCAN_B ((NROW + 255) / 256)  // 313
#define LDW 136                   // padded LDS row stride in bf16 units

typedef __attribute__((ext_vector_type(8))) short short8;
typedef __attribute__((ext_vector_type(4))) float f32x4;

__device__ __forceinline__ short f2bf(float f) {
    unsigned u = __float_as_uint(f);
    unsigned r = u + 0x7FFFu + ((u >> 16) & 1u);   // RNE
    return (short)(r >> 16);
}
__device__ __forceinline__ float bf2f(unsigned s) {
    return __uint_as_float(s << 16);
}

// ---------- per-row degree (float) + edge count (int) ----------
__global__ __launch_bounds__(256) void k_deg(const float* __restrict__ adj,
                                             const int* __restrict__ src,
                                             float* __restrict__ deg,
                                             int* __restrict__ cnt) {
    int idx = blockIdx.x * 256 + threadIdx.x;
    int b = idx / NEDGE;
    int r = b * NNODE + src[idx];
    atomicAdd(&deg[r], adj[idx]);
    atomicAdd(&cnt[r], 1);
}

// ---------- hierarchical exclusive scan of cnt -> rowptr/cursor ----------
__global__ __launch_bounds__(256) void k_scan1(const int* __restrict__ cnt,
                                               int* __restrict__ incl,   // = rowptr buf
                                               int* __restrict__ bsum) {
    __shared__ int s[256];
    int t = threadIdx.x, g = blockIdx.x * 256 + t;
    int v = (g < NROW) ? cnt[g] : 0;
    s[t] = v; __syncthreads();
    for (int off = 1; off < 256; off <<= 1) {
        int a = s[t]; int add = (t >= off) ? s[t - off] : 0;
        __syncthreads();
        s[t] = a + add;
        __syncthreads();
    }
    if (g < NROW) incl[g] = s[t];
    if (t == 255) bsum[blockIdx.x] = s[255];
}
__global__ __launch_bounds__(512) void k_scan2(const int* __restrict__ bsum,
                                               int* __restrict__ boff) {
    __shared__ int s[512];
    int t = threadIdx.x;
    int v = (t < SCAN_B) ? bsum[t] : 0;
    s[t] = v; __syncthreads();
    for (int off = 1; off < 512; off <<= 1) {
        int a = s[t]; int add = (t >= off) ? s[t - off] : 0;
        __syncthreads();
        s[t] = a + add;
        __syncthreads();
    }
    if (t < SCAN_B) boff[t] = s[t] - v;   // exclusive
}
__global__ __launch_bounds__(256) void k_scan3(const int* __restrict__ cnt,
                                               const int* __restrict__ boff,
                                               int* __restrict__ rowptr,  // holds incl, rewritten
                                               int* __restrict__ cursor) {
    int g = blockIdx.x * 256 + threadIdx.x;
    if (g >= NROW) return;
    int e = rowptr[g] - cnt[g] + boff[blockIdx.x];
    rowptr[g] = e; cursor[g] = e;
}

// ---------- bucket edges by (b, src) ----------
__global__ __launch_bounds__(256) void k_scatter(const int* __restrict__ src,
                                                 int* __restrict__ cursor,
                                                 int* __restrict__ perm) {
    int idx = blockIdx.x * 256 + threadIdx.x;
    int b = idx / NEDGE;
    int r = b * NNODE + src[idx];
    int pos = atomicAdd(&cursor[r], 1);
    perm[pos] = idx;
}

// ---------- convert 3 weight matrices to bf16, transposed: w[n*128+k] = W[k][n] ----------
__global__ __launch_bounds__(256) void k_wcvt(const float* __restrict__ th,
                                              const float* __restrict__ Wt,
                                              const float* __restrict__ Wh,
                                              short* __restrict__ wbf) {
    int i = blockIdx.x * 256 + threadIdx.x;   // 3*16384 threads
    int w = i >> 14, idx = i & 16383;
    int n = idx >> 7, k = idx & 127;
    const float* W = (w == 0) ? th : ((w == 1) ? Wt : Wh);
    wbf[i] = f2bf(W[k * HD + n]);             // i = w*16384 + n*128 + k
}

// ---------- Y[row,:] = bf16( (x@theta) * rsqrt(deg+1e-6) ) via MFMA ----------
__global__ __launch_bounds__(256) void k_theta(const float* __restrict__ x,
                                               const short* __restrict__ thT,
                                               const float* __restrict__ deg,
                                               short* __restrict__ Y) {
    __shared__ short lb[HD * LDW];            // 34816 B
    int tx = threadIdx.x;
    for (int i = tx; i < HD * 16; i += 256) { // 16B chunks: n = i>>4, kc = (i&15)*8
        int n = i >> 4, kc = (i & 15) << 3;
        *(float4*)(&lb[n * LDW + kc]) = *(const float4*)(&thT[n * HD + kc]);
    }
    __syncthreads();

    int wv = tx >> 6, l = tx & 63;
    long row0 = (long)blockIdx.x * 64 + wv * 16;
    int mrow = l & 15, kg = l >> 4;           // kg 0..3
    const float* xp = x + (row0 + mrow) * HD + kg * 8;

    f32x4 acc[8];
    #pragma unroll
    for (int f = 0; f < 8; ++f) acc[f] = (f32x4){0.f, 0.f, 0.f, 0.f};

    #pragma unroll
    for (int c = 0; c < 4; ++c) {
        float4 a0 = *(const float4*)(xp + c * 32);
        float4 a1 = *(const float4*)(xp + c * 32 + 4);
        short8 a;
        a[0]=f2bf(a0.x); a[1]=f2bf(a0.y); a[2]=f2bf(a0.z); a[3]=f2bf(a0.w);
        a[4]=f2bf(a1.x); a[5]=f2bf(a1.y); a[6]=f2bf(a1.z); a[7]=f2bf(a1.w);
        #pragma unroll
        for (int f = 0; f < 8; ++f) {
            short8 b = *(short8*)(&lb[(16 * f + mrow) * LDW + c * 32 + kg * 8]);
            acc[f] = __builtin_amdgcn_mfma_f32_16x16x32_bf16(a, b, acc[f], 0, 0, 0);
        }
    }
    float nr[4];
    #pragma unroll
    for (int r = 0; r < 4; ++r) nr[r] = rsqrtf(deg[row0 + kg * 4 + r] + 1e-6f);
    #pragma unroll
    for (int f = 0; f < 8; ++f)
        #pragma unroll
        for (int r = 0; r < 4; ++r)
            Y[(row0 + kg * 4 + r) * HD + 16 * f + mrow] = f2bf(acc[f][r] * nr[r]);
}

// ---------- gather SpMM: out[r,:] = nrm * sum adj * Y[b,dst,:]  (bf16 Y, unroll 4) ----------
__global__ __launch_bounds__(256) void k_gather(const int* __restrict__ rowptr,
                                                const int* __restrict__ cnt,
                                                const int* __restrict__ perm,
                                                const int* __restrict__ dst,
                                                const float* __restrict__ adj,
                                                const short* __restrict__ Y,
                                                const float* __restrict__ deg,
                                                float* __restrict__ out) {
    int wave = threadIdx.x >> 6, lane = threadIdx.x & 63;
    long r = (long)blockIdx.x * 4 + wave;
    int b = (int)(r / NNODE);
    const short* Yb = Y + (long)b * NNODE * HD + 2 * lane;
    int p0 = rowptr[r], n = cnt[r];
    float ax = 0.f, ay = 0.f;
    int i = 0;
    for (; i + 4 <= n; i += 4) {
        int e0 = perm[p0+i], e1 = perm[p0+i+1], e2 = perm[p0+i+2], e3 = perm[p0+i+3];
        int d0 = dst[e0], d1 = dst[e1], d2 = dst[e2], d3 = dst[e3];
        float v0 = adj[e0], v1 = adj[e1], v2 = adj[e2], v3 = adj[e3];
        unsigned y0 = *(const unsigned*)(Yb + (long)d0 * HD);
        unsigned y1 = *(const unsigned*)(Yb + (long)d1 * HD);
        unsigned y2 = *(const unsigned*)(Yb + (long)d2 * HD);
        unsigned y3 = *(const unsigned*)(Yb + (long)d3 * HD);
        ax += v0 * bf2f(y0 & 0xffffu); ay += v0 * bf2f(y0 >> 16);
        ax += v1 * bf2f(y1 & 0xffffu); ay += v1 * bf2f(y1 >> 16);
        ax += v2 * bf2f(y2 & 0xffffu); ay += v2 * bf2f(y2 >> 16);
        ax += v3 * bf2f(y3 & 0xffffu); ay += v3 * bf2f(y3 >> 16);
    }
    for (; i < n; ++i) {
        int e = perm[p0 + i];
        int d = dst[e];
        float v = adj[e];
        unsigned y = *(const unsigned*)(Yb + (long)d * HD);
        ax += v * bf2f(y & 0xffffu); ay += v * bf2f(y >> 16);
    }
    float nrm = rsqrtf(deg[r] + 1e-6f);
    ((float2*)(out + r * HD))[lane] = make_float2(ax * nrm, ay * nrm);
}

// ---------- out = sigmoid(x@Wt+b) * z + (1-g) * (x@Wh)  via MFMA ----------
__global__ __launch_bounds__(256) void k_final(const float* __restrict__ x,
                                               const short* __restrict__ WtT,
                                               const short* __restrict__ WhT,
                                               const float* __restrict__ bt,
                                               float* __restrict__ out) {
    __shared__ short lb[2 * HD * LDW];        // 69632 B
    int tx = threadIdx.x;
    for (int i = tx; i < HD * 16; i += 256) {
        int n = i >> 4, kc = (i & 15) << 3;
        *(float4*)(&lb[n * LDW + kc])            = *(const float4*)(&WtT[n * HD + kc]);
        *(float4*)(&lb[HD * LDW + n * LDW + kc]) = *(const float4*)(&WhT[n * HD + kc]);
    }
    __syncthreads();

    int wv = tx >> 6, l = tx & 63;
    long row0 = (long)blockIdx.x * 64 + wv * 16;
    int mrow = l & 15, kg = l >> 4;
    const float* xp = x + (row0 + mrow) * HD + kg * 8;

    f32x4 at[8], ah[8];
    #pragma unroll
    for (int f = 0; f < 8; ++f) { at[f] = (f32x4){0.f,0.f,0.f,0.f}; ah[f] = (f32x4){0.f,0.f,0.f,0.f}; }

    #pragma unroll
    for (int c = 0; c < 4; ++c) {
        float4 a0 = *(const float4*)(xp + c * 32);
        float4 a1 = *(const float4*)(xp + c * 32 + 4);
        short8 a;
        a[0]=f2bf(a0.x); a[1]=f2bf(a0.y); a[2]=f2bf(a0.z); a[3]=f2bf(a0.w);
        a[4]=f2bf(a1.x); a[5]=f2bf(a1.y); a[6]=f2bf(a1.z); a[7]=f2bf(a1.w);
        #pragma unroll
        for (int f = 0; f < 8; ++f) {
            short8 b0 = *(short8*)(&lb[(16 * f + mrow) * LDW + c * 32 + kg * 8]);
            short8 b1 = *(short8*)(&lb[HD * LDW + (16 * f + mrow) * LDW + c * 32 + kg * 8]);
            at[f] = __builtin_amdgcn_mfma_f32_16x16x32_bf16(a, b0, at[f], 0, 0, 0);
            ah[f] = __builtin_amdgcn_mfma_f32_16x16x32_bf16(a, b1, ah[f], 0, 0, 0);
        }
    }
    #pragma unroll
    for (int f = 0; f < 8; ++f) {
        float bb = bt[16 * f + mrow];
        #pragma unroll
        for (int r = 0; r < 4; ++r) {
            long row = row0 + kg * 4 + r;
            float* op = out + row * HD + 16 * f + mrow;
            float z = *op;
            float g = 1.f / (1.f + __expf(-(at[f][r] + bb)));
            *op = g * z + (1.f - g) * ah[f][r];
        }
    }
}

extern "C" void kernel_launch(void* const* d_in, const int* in_sizes, int n_in,
                              void* d_out, int out_size, void* d_ws, size_t ws_size,
                              hipStream_t stream) {
    const float* x     = (const float*)d_in[0];
    const float* adj   = (const float*)d_in[1];
    const int*   src   = (const int*)d_in[2];
    const int*   dst   = (const int*)d_in[3];
    const float* Wt    = (const float*)d_in[4];
    const float* bt    = (const float*)d_in[5];
    const float* Wh    = (const float*)d_in[6];
    const float* theta = (const float*)d_in[7];
    float* out = (float*)d_out;

    // workspace layout (~53 MB)
    float* deg    = (float*)d_ws;               // NROW f
    int*   cnt    = (int*)(deg + NROW);         // NROW
    int*   rowptr = cnt + NROW;                 // NROW (also scan temp)
    int*   cursor = rowptr + NROW;              // NROW
    int*   perm   = cursor + NROW;              // NEDG_TOT
    int*   bsum   = perm + NEDG_TOT;            // 512
    int*   boff   = bsum + 512;                 // 512
    short* wbf    = (short*)(boff + 512);       // 3*16384 bf16 (thT, WtT, WhT)
    short* Y      = wbf + 3 * 16384;            // NROW*HD bf16 (~20.5 MB)

    hipMemsetAsync(deg, 0, (size_t)NROW * 2 * sizeof(float), stream); // deg + cnt

    k_deg    <<<NEDG_TOT / 256, 256, 0, stream>>>(adj, src, deg, cnt);
    k_scan1  <<<SCAN_B, 256, 0, stream>>>(cnt, rowptr, bsum);
    k_scan2  <<<1, 512, 0, stream>>>(bsum, boff);
    k_scan3  <<<SCAN_B, 256, 0, stream>>>(cnt, boff, rowptr, cursor);
    k_scatter<<<NEDG_TOT / 256, 256, 0, stream>>>(src, cursor, perm);
    k_wcvt   <<<3 * 16384 / 256, 256, 0, stream>>>(theta, Wt, Wh, wbf);
    k_theta  <<<NROW / 64, 256, 0, stream>>>(x, wbf, deg, Y);
    k_gather <<<NROW / 4, 256, 0, stream>>>(rowptr, cnt, perm, dst, adj, Y, deg, out);
    k_final  <<<NROW / 64, 256, 0, stream>>>(x, wbf + 16384, wbf + 2 * 16384, bt, out);
}

// Round 4
// 214.025 us; speedup vs baseline: 21.3275x; 2.6636x over previous
//
#include <hip/hip_runtime.h>

#define BATCH 8
#define NNODE 10000
#define NEDGE 320000
#define HD    128
#define NROW  (BATCH * NNODE)       // 80000 rows
#define NEDG_TOT (BATCH * NEDGE)    // 2.56M edges
#define SCAN_B ((NROW + 255) / 256) // 313
#define LDW 136                     // padded LDS row stride (bf16) for weight tiles
#define KB  32                      // count/scatter blocks per batch
#define CEB (NEDGE / KB)            // 10000 edges per block

typedef __attribute__((ext_vector_type(8))) short short8;
typedef __attribute__((ext_vector_type(4))) float f32x4;

__device__ __forceinline__ short f2bf(float f) {
    unsigned u = __float_as_uint(f);
    unsigned r = u + 0x7FFFu + ((u >> 16) & 1u);   // RNE
    return (short)(r >> 16);
}
__device__ __forceinline__ float bf2f(unsigned s) {
    return __uint_as_float(s << 16);
}

// ---------- pass 1: per-block LDS histogram (count + degree), no global atomics ----------
__global__ __launch_bounds__(256) void k_cnt(const float* __restrict__ adj,
                                             const int* __restrict__ src,
                                             int* __restrict__ bcnt,
                                             float* __restrict__ bdeg) {
    __shared__ int   scnt[NNODE];   // 40 KB
    __shared__ float sdeg[NNODE];   // 40 KB
    int t = threadIdx.x, blk = blockIdx.x;
    for (int i = t; i < NNODE; i += 256) { scnt[i] = 0; sdeg[i] = 0.f; }
    __syncthreads();
    int b = blk >> 5, kb = blk & (KB - 1);
    long e0 = (long)b * NEDGE + (long)kb * CEB;
    for (int i = t; i < CEB; i += 256) {
        long e = e0 + i;
        int s = src[e];
        atomicAdd(&scnt[s], 1);
        atomicAdd(&sdeg[s], adj[e]);
    }
    __syncthreads();
    int*   bc = bcnt + (long)blk * NNODE;
    float* bd = bdeg + (long)blk * NNODE;
    for (int i = t; i < NNODE; i += 256) { bc[i] = scnt[i]; bd[i] = sdeg[i]; }
}

// ---------- pass 2a: row totals + degree (no atomics) ----------
__global__ __launch_bounds__(256) void k_sum(const int* __restrict__ bcnt,
                                             const float* __restrict__ bdeg,
                                             int* __restrict__ total,
                                             float* __restrict__ deg) {
    int r = blockIdx.x * 256 + threadIdx.x;
    if (r >= NROW) return;
    int b = r / NNODE, n = r % NNODE;
    const int*   bc = bcnt + (long)b * KB * NNODE + n;
    const float* bd = bdeg + (long)b * KB * NNODE + n;
    int s = 0; float ds = 0.f;
    #pragma unroll
    for (int k = 0; k < KB; ++k) {
        s  += bc[(long)k * NNODE];
        ds += bd[(long)k * NNODE];
    }
    total[r] = s; deg[r] = ds;
}

// ---------- hierarchical exclusive scan of total -> rowptr ----------
__global__ __launch_bounds__(256) void k_scan1(const int* __restrict__ total,
                                               int* __restrict__ incl,
                                               int* __restrict__ bsum) {
    __shared__ int s[256];
    int t = threadIdx.x, g = blockIdx.x * 256 + t;
    int v = (g < NROW) ? total[g] : 0;
    s[t] = v; __syncthreads();
    for (int off = 1; off < 256; off <<= 1) {
        int a = s[t]; int add = (t >= off) ? s[t - off] : 0;
        __syncthreads();
        s[t] = a + add;
        __syncthreads();
    }
    if (g < NROW) incl[g] = s[t];
    if (t == 255) bsum[blockIdx.x] = s[255];
}
__global__ __launch_bounds__(512) void k_scan2(const int* __restrict__ bsum,
                                               int* __restrict__ boffs) {
    __shared__ int s[512];
    int t = threadIdx.x;
    int v = (t < SCAN_B) ? bsum[t] : 0;
    s[t] = v; __syncthreads();
    for (int off = 1; off < 512; off <<= 1) {
        int a = s[t]; int add = (t >= off) ? s[t - off] : 0;
        __syncthreads();
        s[t] = a + add;
        __syncthreads();
    }
    if (t < SCAN_B) boffs[t] = s[t] - v;   // exclusive
}
__global__ __launch_bounds__(256) void k_scan3(const int* __restrict__ total,
                                               const int* __restrict__ boffs,
                                               int* __restrict__ rowptr) {
    int g = blockIdx.x * 256 + threadIdx.x;
    if (g >= NROW) return;
    rowptr[g] = rowptr[g] - total[g] + boffs[blockIdx.x];   // incl -> excl
}

// ---------- pass 2b: per-(block,row) base offsets, bcnt rewritten in place ----------
__global__ __launch_bounds__(256) void k_boff(int* __restrict__ bcnt,
                                              const int* __restrict__ rowptr) {
    int r = blockIdx.x * 256 + threadIdx.x;
    if (r >= NROW) return;
    int b = r / NNODE, n = r % NNODE;
    int* bc = bcnt + (long)b * KB * NNODE + n;
    int run = rowptr[r];
    #pragma unroll
    for (int k = 0; k < KB; ++k) {
        int c = bc[(long)k * NNODE];
        bc[(long)k * NNODE] = run;
        run += c;
    }
}

// ---------- pass 3: scatter edges into (dst, adj) pairs, LDS cursors only ----------
__global__ __launch_bounds__(256) void k_scat(const float* __restrict__ adj,
                                              const int* __restrict__ src,
                                              const int* __restrict__ dst,
                                              const int* __restrict__ boff,
                                              int2* __restrict__ epair) {
    __shared__ int cur[NNODE];      // 40 KB
    int t = threadIdx.x, blk = blockIdx.x;
    const int* bo = boff + (long)blk * NNODE;
    for (int i = t; i < NNODE; i += 256) cur[i] = bo[i];
    __syncthreads();
    int b = blk >> 5, kb = blk & (KB - 1);
    long e0 = (long)b * NEDGE + (long)kb * CEB;
    for (int i = t; i < CEB; i += 256) {
        long e = e0 + i;
        int s = src[e];
        int p = atomicAdd(&cur[s], 1);
        epair[p] = make_int2(dst[e], __float_as_int(adj[e]));
    }
}

// ---------- weights -> bf16 transposed: w[n*128+k] = W[k][n] ----------
__global__ __launch_bounds__(256) void k_wcvt(const float* __restrict__ th,
                                              const float* __restrict__ Wt,
                                              const float* __restrict__ Wh,
                                              short* __restrict__ wbf) {
    int i = blockIdx.x * 256 + threadIdx.x;
    int w = i >> 14, idx = i & 16383;
    int n = idx >> 7, k = idx & 127;
    const float* W = (w == 0) ? th : ((w == 1) ? Wt : Wh);
    wbf[i] = f2bf(W[k * HD + n]);
}

// ---------- Y = bf16( (x@theta) * rsqrt(deg+1e-6) ) via MFMA ----------
__global__ __launch_bounds__(256) void k_theta(const float* __restrict__ x,
                                               const short* __restrict__ thT,
                                               const float* __restrict__ deg,
                                               short* __restrict__ Y) {
    __shared__ short lb[HD * LDW];
    int tx = threadIdx.x;
    for (int i = tx; i < HD * 16; i += 256) {
        int n = i >> 4, kc = (i & 15) << 3;
        *(float4*)(&lb[n * LDW + kc]) = *(const float4*)(&thT[n * HD + kc]);
    }
    __syncthreads();

    int wv = tx >> 6, l = tx & 63;
    long row0 = (long)blockIdx.x * 64 + wv * 16;
    int mrow = l & 15, kg = l >> 4;
    const float* xp = x + (row0 + mrow) * HD + kg * 8;

    f32x4 acc[8];
    #pragma unroll
    for (int f = 0; f < 8; ++f) acc[f] = (f32x4){0.f, 0.f, 0.f, 0.f};

    #pragma unroll
    for (int c = 0; c < 4; ++c) {
        float4 a0 = *(const float4*)(xp + c * 32);
        float4 a1 = *(const float4*)(xp + c * 32 + 4);
        short8 a;
        a[0]=f2bf(a0.x); a[1]=f2bf(a0.y); a[2]=f2bf(a0.z); a[3]=f2bf(a0.w);
        a[4]=f2bf(a1.x); a[5]=f2bf(a1.y); a[6]=f2bf(a1.z); a[7]=f2bf(a1.w);
        #pragma unroll
        for (int f = 0; f < 8; ++f) {
            short8 b = *(short8*)(&lb[(16 * f + mrow) * LDW + c * 32 + kg * 8]);
            acc[f] = __builtin_amdgcn_mfma_f32_16x16x32_bf16(a, b, acc[f], 0, 0, 0);
        }
    }
    float nr[4];
    #pragma unroll
    for (int r = 0; r < 4; ++r) nr[r] = rsqrtf(deg[row0 + kg * 4 + r] + 1e-6f);
    #pragma unroll
    for (int f = 0; f < 8; ++f)
        #pragma unroll
        for (int r = 0; r < 4; ++r)
            Y[(row0 + kg * 4 + r) * HD + 16 * f + mrow] = f2bf(acc[f][r] * nr[r]);
}

// ---------- gather SpMM, XCD-swizzled (batch = blockIdx%8 -> per-XCD L2-resident Y) ----------
__global__ __launch_bounds__(256) void k_gather(const int* __restrict__ rowptr,
                                                const int* __restrict__ total,
                                                const int2* __restrict__ epair,
                                                const short* __restrict__ Y,
                                                const float* __restrict__ deg,
                                                float* __restrict__ out) {
    int batch = blockIdx.x & 7;
    int ib    = blockIdx.x >> 3;            // 0..2499
    int wave = threadIdx.x >> 6, lane = threadIdx.x & 63;
    long r = (long)batch * NNODE + ib * 4 + wave;
    const short* Yb = Y + (long)batch * NNODE * HD + 2 * lane;
    int p0 = rowptr[r], n = total[r];
    const int2* ep = epair + p0;
    float ax = 0.f, ay = 0.f;
    int i = 0;
    for (; i + 4 <= n; i += 4) {
        int2 e0 = ep[i], e1 = ep[i+1], e2 = ep[i+2], e3 = ep[i+3];
        unsigned y0 = *(const unsigned*)(Yb + (long)e0.x * HD);
        unsigned y1 = *(const unsigned*)(Yb + (long)e1.x * HD);
        unsigned y2 = *(const unsigned*)(Yb + (long)e2.x * HD);
        unsigned y3 = *(const unsigned*)(Yb + (long)e3.x * HD);
        float v0 = __int_as_float(e0.y), v1 = __int_as_float(e1.y);
        float v2 = __int_as_float(e2.y), v3 = __int_as_float(e3.y);
        ax += v0 * bf2f(y0 & 0xffffu); ay += v0 * bf2f(y0 >> 16);
        ax += v1 * bf2f(y1 & 0xffffu); ay += v1 * bf2f(y1 >> 16);
        ax += v2 * bf2f(y2 & 0xffffu); ay += v2 * bf2f(y2 >> 16);
        ax += v3 * bf2f(y3 & 0xffffu); ay += v3 * bf2f(y3 >> 16);
    }
    for (; i < n; ++i) {
        int2 e = ep[i];
        unsigned y = *(const unsigned*)(Yb + (long)e.x * HD);
        float v = __int_as_float(e.y);
        ax += v * bf2f(y & 0xffffu); ay += v * bf2f(y >> 16);
    }
    float nrm = rsqrtf(deg[r] + 1e-6f);
    ((float2*)(out + r * HD))[lane] = make_float2(ax * nrm, ay * nrm);
}

// ---------- out = sigmoid(x@Wt+b) * z + (1-g) * (x@Wh) via MFMA ----------
__global__ __launch_bounds__(256) void k_final(const float* __restrict__ x,
                                               const short* __restrict__ WtT,
                                               const short* __restrict__ WhT,
                                               const float* __restrict__ bt,
                                               float* __restrict__ out) {
    __shared__ short lb[2 * HD * LDW];
    int tx = threadIdx.x;
    for (int i = tx; i < HD * 16; i += 256) {
        int n = i >> 4, kc = (i & 15) << 3;
        *(float4*)(&lb[n * LDW + kc])            = *(const float4*)(&WtT[n * HD + kc]);
        *(float4*)(&lb[HD * LDW + n * LDW + kc]) = *(const float4*)(&WhT[n * HD + kc]);
    }
    __syncthreads();

    int wv = tx >> 6, l = tx & 63;
    long row0 = (long)blockIdx.x * 64 + wv * 16;
    int mrow = l & 15, kg = l >> 4;
    const float* xp = x + (row0 + mrow) * HD + kg * 8;

    f32x4 at[8], ah[8];
    #pragma unroll
    for (int f = 0; f < 8; ++f) { at[f] = (f32x4){0.f,0.f,0.f,0.f}; ah[f] = (f32x4){0.f,0.f,0.f,0.f}; }

    #pragma unroll
    for (int c = 0; c < 4; ++c) {
        float4 a0 = *(const float4*)(xp + c * 32);
        float4 a1 = *(const float4*)(xp + c * 32 + 4);
        short8 a;
        a[0]=f2bf(a0.x); a[1]=f2bf(a0.y); a[2]=f2bf(a0.z); a[3]=f2bf(a0.w);
        a[4]=f2bf(a1.x); a[5]=f2bf(a1.y); a[6]=f2bf(a1.z); a[7]=f2bf(a1.w);
        #pragma unroll
        for (int f = 0; f < 8; ++f) {
            short8 b0 = *(short8*)(&lb[(16 * f + mrow) * LDW + c * 32 + kg * 8]);
            short8 b1 = *(short8*)(&lb[HD * LDW + (16 * f + mrow) * LDW + c * 32 + kg * 8]);
            at[f] = __builtin_amdgcn_mfma_f32_16x16x32_bf16(a, b0, at[f], 0, 0, 0);
            ah[f] = __builtin_amdgcn_mfma_f32_16x16x32_bf16(a, b1, ah[f], 0, 0, 0);
        }
    }
    #pragma unroll
    for (int f = 0; f < 8; ++f) {
        float bb = bt[16 * f + mrow];
        #pragma unroll
        for (int r = 0; r < 4; ++r) {
            long row = row0 + kg * 4 + r;
            float* op = out + row * HD + 16 * f + mrow;
            float z = *op;
            float g = 1.f / (1.f + __expf(-(at[f][r] + bb)));
            *op = g * z + (1.f - g) * ah[f][r];
        }
    }
}

extern "C" void kernel_launch(void* const* d_in, const int* in_sizes, int n_in,
                              void* d_out, int out_size, void* d_ws, size_t ws_size,
                              hipStream_t stream) {
    const float* x     = (const float*)d_in[0];
    const float* adj   = (const float*)d_in[1];
    const int*   src   = (const int*)d_in[2];
    const int*   dst   = (const int*)d_in[3];
    const float* Wt    = (const float*)d_in[4];
    const float* bt    = (const float*)d_in[5];
    const float* Wh    = (const float*)d_in[6];
    const float* theta = (const float*)d_in[7];
    float* out = (float*)d_out;

    // workspace (~42 MB); Y aliases bcnt+bdeg (dead after k_scat)
    float* deg    = (float*)d_ws;                    // NROW
    int*   total  = (int*)(deg + NROW);              // NROW
    int*   rowptr = total + NROW;                    // NROW
    int*   bsum   = rowptr + NROW;                   // 512
    int*   boffs  = bsum + 512;                      // 512
    short* wbf    = (short*)(boffs + 512);           // 3*16384 bf16
    int*   bcnt   = (int*)(wbf + 3 * 16384);         // 8*KB*NNODE ints   (10.24 MB)
    float* bdeg   = (float*)(bcnt + 8 * KB * NNODE); // 8*KB*NNODE floats (10.24 MB)
    short* Y      = (short*)bcnt;                    // NROW*HD bf16 (20.48 MB, aliases)
    int2*  epair  = (int2*)(bdeg + 8 * KB * NNODE);  // NEDG_TOT int2 (20.48 MB)

    k_cnt  <<<8 * KB, 256, 0, stream>>>(adj, src, bcnt, bdeg);
    k_sum  <<<SCAN_B, 256, 0, stream>>>(bcnt, bdeg, total, deg);
    k_scan1<<<SCAN_B, 256, 0, stream>>>(total, rowptr, bsum);
    k_scan2<<<1, 512, 0, stream>>>(bsum, boffs);
    k_scan3<<<SCAN_B, 256, 0, stream>>>(total, boffs, rowptr);
    k_boff <<<SCAN_B, 256, 0, stream>>>(bcnt, rowptr);
    k_scat <<<8 * KB, 256, 0, stream>>>(adj, src, dst, bcnt, epair);
    k_wcvt <<<3 * 16384 / 256, 256, 0, stream>>>(theta, Wt, Wh, wbf);
    k_theta<<<NROW / 64, 256, 0, stream>>>(x, wbf, deg, Y);
    k_gather<<<NROW / 4, 256, 0, stream>>>(rowptr, total, epair, Y, deg, out);
    k_final<<<NROW / 64, 256, 0, stream>>>(x, wbf + 16384, wbf + 2 * 16384, bt, out);
}

// Round 5
// 180.273 us; speedup vs baseline: 25.3206x; 1.1872x over previous
//
#include <hip/hip_runtime.h>

#define BATCH 8
#define NNODE 10000
#define NEDGE 320000
#define HD    128
#define NROW  (BATCH * NNODE)       // 80000 rows
#define NEDG_TOT (BATCH * NEDGE)    // 2.56M edges
#define SCAN_B ((NROW + 255) / 256) // 313
#define LDW 136                     // padded LDS row stride (bf16)
#define KB  32                      // count/scatter blocks per batch
#define CEB (NEDGE / KB)            // 10000 edges per block

typedef __attribute__((ext_vector_type(8))) short short8;
typedef __attribute__((ext_vector_type(4))) float f32x4;

__device__ __forceinline__ short f2bf(float f) {
    unsigned u = __float_as_uint(f);
    unsigned r = u + 0x7FFFu + ((u >> 16) & 1u);   // RNE
    return (short)(r >> 16);
}
__device__ __forceinline__ float bf2f(unsigned s) { return __uint_as_float(s << 16); }
__device__ __forceinline__ float bflo(unsigned y) { return __uint_as_float(y << 16); }
__device__ __forceinline__ float bfhi(unsigned y) { return __uint_as_float(y & 0xffff0000u); }

// ---------- pass 1: per-block LDS histogram (count + degree) ----------
__global__ __launch_bounds__(256) void k_cnt(const float* __restrict__ adj,
                                             const int* __restrict__ src,
                                             int* __restrict__ bcnt,
                                             float* __restrict__ bdeg) {
    __shared__ int   scnt[NNODE];
    __shared__ float sdeg[NNODE];
    int t = threadIdx.x, blk = blockIdx.x;
    for (int i = t; i < NNODE; i += 256) { scnt[i] = 0; sdeg[i] = 0.f; }
    __syncthreads();
    int b = blk >> 5, kb = blk & (KB - 1);
    long e0 = (long)b * NEDGE + (long)kb * CEB;
    for (int i = t; i < CEB; i += 256) {
        long e = e0 + i;
        int s = src[e];
        atomicAdd(&scnt[s], 1);
        atomicAdd(&sdeg[s], adj[e]);
    }
    __syncthreads();
    int*   bc = bcnt + (long)blk * NNODE;
    float* bd = bdeg + (long)blk * NNODE;
    for (int i = t; i < NNODE; i += 256) { bc[i] = scnt[i]; bd[i] = sdeg[i]; }
}

// ---------- pass 2a: row totals + degree ----------
__global__ __launch_bounds__(256) void k_sum(const int* __restrict__ bcnt,
                                             const float* __restrict__ bdeg,
                                             int* __restrict__ total,
                                             float* __restrict__ deg) {
    int r = blockIdx.x * 256 + threadIdx.x;
    if (r >= NROW) return;
    int b = r / NNODE, n = r % NNODE;
    const int*   bc = bcnt + (long)b * KB * NNODE + n;
    const float* bd = bdeg + (long)b * KB * NNODE + n;
    int s = 0; float ds = 0.f;
    #pragma unroll
    for (int k = 0; k < KB; ++k) {
        s  += bc[(long)k * NNODE];
        ds += bd[(long)k * NNODE];
    }
    total[r] = s; deg[r] = ds;
}

// ---------- scan over PADDED counts (each bucket rounded to even -> 16B-aligned) ----------
__global__ __launch_bounds__(256) void k_scan1(const int* __restrict__ total,
                                               int* __restrict__ incl,
                                               int* __restrict__ bsum) {
    __shared__ int s[256];
    int t = threadIdx.x, g = blockIdx.x * 256 + t;
    int v = (g < NROW) ? ((total[g] + 1) & ~1) : 0;
    s[t] = v; __syncthreads();
    for (int off = 1; off < 256; off <<= 1) {
        int a = s[t]; int add = (t >= off) ? s[t - off] : 0;
        __syncthreads();
        s[t] = a + add;
        __syncthreads();
    }
    if (g < NROW) incl[g] = s[t];
    if (t == 255) bsum[blockIdx.x] = s[255];
}
__global__ __launch_bounds__(512) void k_scan2(const int* __restrict__ bsum,
                                               int* __restrict__ boffs) {
    __shared__ int s[512];
    int t = threadIdx.x;
    int v = (t < SCAN_B) ? bsum[t] : 0;
    s[t] = v; __syncthreads();
    for (int off = 1; off < 512; off <<= 1) {
        int a = s[t]; int add = (t >= off) ? s[t - off] : 0;
        __syncthreads();
        s[t] = a + add;
        __syncthreads();
    }
    if (t < SCAN_B) boffs[t] = s[t] - v;
}

// ---------- incl->excl rowptr + per-(block,row) base offsets (merged scan3+boff) ----------
__global__ __launch_bounds__(256) void k_boff(const int* __restrict__ total,
                                              const int* __restrict__ boffs,
                                              int* __restrict__ rowptr,
                                              int* __restrict__ bcnt) {
    int r = blockIdx.x * 256 + threadIdx.x;
    if (r >= NROW) return;
    int pt = (total[r] + 1) & ~1;
    int excl = rowptr[r] - pt + boffs[blockIdx.x];
    rowptr[r] = excl;
    int b = r / NNODE, n = r % NNODE;
    int* bc = bcnt + (long)b * KB * NNODE + n;
    int run = excl;
    #pragma unroll
    for (int k = 0; k < KB; ++k) {
        int c = bc[(long)k * NNODE];
        bc[(long)k * NNODE] = run;
        run += c;
    }
}

// ---------- pass 3: scatter edges into (dst, adj) pairs, LDS cursors only ----------
__global__ __launch_bounds__(256) void k_scat(const float* __restrict__ adj,
                                              const int* __restrict__ src,
                                              const int* __restrict__ dst,
                                              const int* __restrict__ boff,
                                              int2* __restrict__ epair) {
    __shared__ int cur[NNODE];
    int t = threadIdx.x, blk = blockIdx.x;
    const int* bo = boff + (long)blk * NNODE;
    for (int i = t; i < NNODE; i += 256) cur[i] = bo[i];
    __syncthreads();
    int b = blk >> 5, kb = blk & (KB - 1);
    long e0 = (long)b * NEDGE + (long)kb * CEB;
    for (int i = t; i < CEB; i += 256) {
        long e = e0 + i;
        int s = src[e];
        int p = atomicAdd(&cur[s], 1);
        epair[p] = make_int2(dst[e], __float_as_int(adj[e]));
    }
}

// ---------- weights -> bf16 transposed ----------
__global__ __launch_bounds__(256) void k_wcvt(const float* __restrict__ th,
                                              const float* __restrict__ Wt,
                                              const float* __restrict__ Wh,
                                              short* __restrict__ wbf) {
    int i = blockIdx.x * 256 + threadIdx.x;
    int w = i >> 14, idx = i & 16383;
    int n = idx >> 7, k = idx & 127;
    const float* W = (w == 0) ? th : ((w == 1) ? Wt : Wh);
    wbf[i] = f2bf(W[k * HD + n]);
}

// ---------- Y = bf16( (x@theta) * rsqrt(deg+1e-6) ) via MFMA ----------
__global__ __launch_bounds__(256) void k_theta(const float* __restrict__ x,
                                               const short* __restrict__ thT,
                                               const float* __restrict__ deg,
                                               short* __restrict__ Y) {
    __shared__ short lb[HD * LDW];
    int tx = threadIdx.x;
    for (int i = tx; i < HD * 16; i += 256) {
        int n = i >> 4, kc = (i & 15) << 3;
        *(float4*)(&lb[n * LDW + kc]) = *(const float4*)(&thT[n * HD + kc]);
    }
    __syncthreads();

    int wv = tx >> 6, l = tx & 63;
    long row0 = (long)blockIdx.x * 64 + wv * 16;
    int mrow = l & 15, kg = l >> 4;
    const float* xp = x + (row0 + mrow) * HD + kg * 8;

    f32x4 acc[8];
    #pragma unroll
    for (int f = 0; f < 8; ++f) acc[f] = (f32x4){0.f, 0.f, 0.f, 0.f};

    #pragma unroll
    for (int c = 0; c < 4; ++c) {
        float4 a0 = *(const float4*)(xp + c * 32);
        float4 a1 = *(const float4*)(xp + c * 32 + 4);
        short8 a;
        a[0]=f2bf(a0.x); a[1]=f2bf(a0.y); a[2]=f2bf(a0.z); a[3]=f2bf(a0.w);
        a[4]=f2bf(a1.x); a[5]=f2bf(a1.y); a[6]=f2bf(a1.z); a[7]=f2bf(a1.w);
        #pragma unroll
        for (int f = 0; f < 8; ++f) {
            short8 b = *(short8*)(&lb[(16 * f + mrow) * LDW + c * 32 + kg * 8]);
            acc[f] = __builtin_amdgcn_mfma_f32_16x16x32_bf16(a, b, acc[f], 0, 0, 0);
        }
    }
    float nr[4];
    #pragma unroll
    for (int r = 0; r < 4; ++r) nr[r] = rsqrtf(deg[row0 + kg * 4 + r] + 1e-6f);
    #pragma unroll
    for (int f = 0; f < 8; ++f)
        #pragma unroll
        for (int r = 0; r < 4; ++r)
            Y[(row0 + kg * 4 + r) * HD + 16 * f + mrow] = f2bf(acc[f][r] * nr[r]);
}

// ---------- gather SpMM, XCD-swizzled; ZB=1 -> bf16 z to zout, ZB=0 -> f32 to out ----------
template<int ZB>
__global__ __launch_bounds__(256) void k_gather(const int* __restrict__ rowptr,
                                                const int* __restrict__ total,
                                                const int2* __restrict__ epair,
                                                const short* __restrict__ Y,
                                                const float* __restrict__ deg,
                                                void* __restrict__ zout) {
    int batch = blockIdx.x & 7;
    int ib    = blockIdx.x >> 3;
    int wave = threadIdx.x >> 6, lane = threadIdx.x & 63;
    long r = (long)batch * NNODE + ib * 4 + wave;
    const short* Yb = Y + (long)batch * NNODE * HD + 2 * lane;
    int p0 = __builtin_amdgcn_readfirstlane(rowptr[r]);   // even -> 16B aligned
    int n  = __builtin_amdgcn_readfirstlane(total[r]);
    const int4* ep4 = (const int4*)(epair + p0);          // wave-uniform stream
    float ax = 0.f, ay = 0.f;
    int i = 0;
    for (; i + 8 <= n; i += 8) {
        int4 eA = ep4[(i >> 1) + 0];
        int4 eB = ep4[(i >> 1) + 1];
        int4 eC = ep4[(i >> 1) + 2];
        int4 eD = ep4[(i >> 1) + 3];
        unsigned y0 = *(const unsigned*)(Yb + (long)eA.x * HD);
        unsigned y1 = *(const unsigned*)(Yb + (long)eA.z * HD);
        unsigned y2 = *(const unsigned*)(Yb + (long)eB.x * HD);
        unsigned y3 = *(const unsigned*)(Yb + (long)eB.z * HD);
        unsigned y4 = *(const unsigned*)(Yb + (long)eC.x * HD);
        unsigned y5 = *(const unsigned*)(Yb + (long)eC.z * HD);
        unsigned y6 = *(const unsigned*)(Yb + (long)eD.x * HD);
        unsigned y7 = *(const unsigned*)(Yb + (long)eD.z * HD);
        float v0 = __int_as_float(eA.y), v1 = __int_as_float(eA.w);
        float v2 = __int_as_float(eB.y), v3 = __int_as_float(eB.w);
        float v4 = __int_as_float(eC.y), v5 = __int_as_float(eC.w);
        float v6 = __int_as_float(eD.y), v7 = __int_as_float(eD.w);
        ax += v0 * bflo(y0); ay += v0 * bfhi(y0);
        ax += v1 * bflo(y1); ay += v1 * bfhi(y1);
        ax += v2 * bflo(y2); ay += v2 * bfhi(y2);
        ax += v3 * bflo(y3); ay += v3 * bfhi(y3);
        ax += v4 * bflo(y4); ay += v4 * bfhi(y4);
        ax += v5 * bflo(y5); ay += v5 * bfhi(y5);
        ax += v6 * bflo(y6); ay += v6 * bfhi(y6);
        ax += v7 * bflo(y7); ay += v7 * bfhi(y7);
    }
    for (; i + 2 <= n; i += 2) {
        int4 eA = ep4[i >> 1];
        unsigned y0 = *(const unsigned*)(Yb + (long)eA.x * HD);
        unsigned y1 = *(const unsigned*)(Yb + (long)eA.z * HD);
        float v0 = __int_as_float(eA.y), v1 = __int_as_float(eA.w);
        ax += v0 * bflo(y0); ay += v0 * bfhi(y0);
        ax += v1 * bflo(y1); ay += v1 * bfhi(y1);
    }
    if (i < n) {
        int2 e = epair[p0 + i];
        unsigned y = *(const unsigned*)(Yb + (long)e.x * HD);
        float v = __int_as_float(e.y);
        ax += v * bflo(y); ay += v * bfhi(y);
    }
    float nrm = rsqrtf(deg[r] + 1e-6f);
    if (ZB) {
        unsigned lo = (unsigned short)f2bf(ax * nrm);
        unsigned hi = (unsigned short)f2bf(ay * nrm);
        ((unsigned*)zout)[r * 64 + lane] = lo | (hi << 16);
    } else {
        ((float2*)((float*)zout + r * HD))[lane] = make_float2(ax * nrm, ay * nrm);
    }
}

// ---------- out = g * z + (1-g) * (x@Wh), g = sigmoid(x@Wt+b); ZB: z bf16 vs f32(out) ----------
template<int ZB>
__global__ __launch_bounds__(256) void k_final(const float* __restrict__ x,
                                               const short* __restrict__ WtT,
                                               const short* __restrict__ WhT,
                                               const float* __restrict__ bt,
                                               const void* __restrict__ zsrc,
                                               float* __restrict__ out) {
    __shared__ short lb[2 * HD * LDW];
    int tx = threadIdx.x;
    for (int i = tx; i < HD * 16; i += 256) {
        int n = i >> 4, kc = (i & 15) << 3;
        *(float4*)(&lb[n * LDW + kc])            = *(const float4*)(&WtT[n * HD + kc]);
        *(float4*)(&lb[HD * LDW + n * LDW + kc]) = *(const float4*)(&WhT[n * HD + kc]);
    }
    __syncthreads();

    int wv = tx >> 6, l = tx & 63;
    long row0 = (long)blockIdx.x * 64 + wv * 16;
    int mrow = l & 15, kg = l >> 4;
    const float* xp = x + (row0 + mrow) * HD + kg * 8;

    f32x4 at[8], ah[8];
    #pragma unroll
    for (int f = 0; f < 8; ++f) { at[f] = (f32x4){0.f,0.f,0.f,0.f}; ah[f] = (f32x4){0.f,0.f,0.f,0.f}; }

    #pragma unroll
    for (int c = 0; c < 4; ++c) {
        float4 a0 = *(const float4*)(xp + c * 32);
        float4 a1 = *(const float4*)(xp + c * 32 + 4);
        short8 a;
        a[0]=f2bf(a0.x); a[1]=f2bf(a0.y); a[2]=f2bf(a0.z); a[3]=f2bf(a0.w);
        a[4]=f2bf(a1.x); a[5]=f2bf(a1.y); a[6]=f2bf(a1.z); a[7]=f2bf(a1.w);
        #pragma unroll
        for (int f = 0; f < 8; ++f) {
            short8 b0 = *(short8*)(&lb[(16 * f + mrow) * LDW + c * 32 + kg * 8]);
            short8 b1 = *(short8*)(&lb[HD * LDW + (16 * f + mrow) * LDW + c * 32 + kg * 8]);
            at[f] = __builtin_amdgcn_mfma_f32_16x16x32_bf16(a, b0, at[f], 0, 0, 0);
            ah[f] = __builtin_amdgcn_mfma_f32_16x16x32_bf16(a, b1, ah[f], 0, 0, 0);
        }
    }
    #pragma unroll
    for (int f = 0; f < 8; ++f) {
        float bb = bt[16 * f + mrow];
        #pragma unroll
        for (int r = 0; r < 4; ++r) {
            long row = row0 + kg * 4 + r;
            long idx = row * HD + 16 * f + mrow;
            float z;
            if (ZB) z = bf2f(((const unsigned short*)zsrc)[idx]);
            else    z = ((const float*)zsrc)[idx];
            float g = 1.f / (1.f + __expf(-(at[f][r] + bb)));
            out[idx] = g * z + (1.f - g) * ah[f][r];
        }
    }
}

extern "C" void kernel_launch(void* const* d_in, const int* in_sizes, int n_in,
                              void* d_out, int out_size, void* d_ws, size_t ws_size,
                              hipStream_t stream) {
    const float* x     = (const float*)d_in[0];
    const float* adj   = (const float*)d_in[1];
    const int*   src   = (const int*)d_in[2];
    const int*   dst   = (const int*)d_in[3];
    const float* Wt    = (const float*)d_in[4];
    const float* bt    = (const float*)d_in[5];
    const float* Wh    = (const float*)d_in[6];
    const float* theta = (const float*)d_in[7];
    float* out = (float*)d_out;

    char* p = (char*)d_ws;
    float* deg    = (float*)p;                 p += (size_t)NROW * 4;
    int*   total  = (int*)p;                   p += (size_t)NROW * 4;
    int*   rowptr = (int*)p;                   p += (size_t)NROW * 4;
    int*   bsum   = (int*)p;                   p += 2048;
    int*   boffs  = (int*)p;                   p += 2048;
    short* wbf    = (short*)p;                 p += 3 * 16384 * 2;
    int*   bcnt   = (int*)p;                   // 8*KB*NNODE ints (10.24 MB)
    short* Y      = (short*)p;                 p += (size_t)8 * KB * NNODE * 4;
    float* bdeg   = (float*)p;                 p += (size_t)8 * KB * NNODE * 4;
    int2*  epair  = (int2*)p;                  p += (size_t)(NEDG_TOT + NROW) * 8;
    unsigned short* zbf = (unsigned short*)p;  p += (size_t)NROW * HD * 2;
    int use_z = ((size_t)(p - (char*)d_ws) <= ws_size);

    k_cnt  <<<8 * KB, 256, 0, stream>>>(adj, src, bcnt, bdeg);
    k_sum  <<<SCAN_B, 256, 0, stream>>>(bcnt, bdeg, total, deg);
    k_scan1<<<SCAN_B, 256, 0, stream>>>(total, rowptr, bsum);
    k_scan2<<<1, 512, 0, stream>>>(bsum, boffs);
    k_boff <<<SCAN_B, 256, 0, stream>>>(total, boffs, rowptr, bcnt);
    k_scat <<<8 * KB, 256, 0, stream>>>(adj, src, dst, bcnt, epair);
    k_wcvt <<<3 * 16384 / 256, 256, 0, stream>>>(theta, Wt, Wh, wbf);
    k_theta<<<NROW / 64, 256, 0, stream>>>(x, wbf, deg, Y);
    if (use_z) {
        k_gather<1><<<NROW / 4, 256, 0, stream>>>(rowptr, total, epair, Y, deg, zbf);
        k_final<1><<<NROW / 64, 256, 0, stream>>>(x, wbf + 16384, wbf + 2 * 16384, bt, zbf, out);
    } else {
        k_gather<0><<<NROW / 4, 256, 0, stream>>>(rowptr, total, epair, Y, deg, out);
        k_final<0><<<NROW / 64, 256, 0, stream>>>(x, wbf + 16384, wbf + 2 * 16384, bt, out, out);
    }
}